// Round 4
// baseline (298.514 us; speedup 1.0000x reference)
//
#include <hip/hip_runtime.h>

typedef __attribute__((ext_vector_type(8))) short short8;
typedef __attribute__((ext_vector_type(8))) unsigned short ushort8;
typedef __attribute__((ext_vector_type(4))) float f32x4;

static __device__ __forceinline__ unsigned short f2bf(float f) {
    union { float f; unsigned int u; } a; a.f = f;
    unsigned int u = a.u;
    return (unsigned short)((u + 0x7fffu + ((u >> 16) & 1u)) >> 16);  // RNE
}

// ---------------- prep: modulated+demodulated weights (bf16) ----------------
__global__ void prep_sumsq(const float* __restrict__ kern,
                           const float* __restrict__ style,
                           float* __restrict__ partial) {
    const int rs = blockIdx.x;   // 0..8
    const int b  = blockIdx.y;   // 0..7
    const int t  = threadIdx.x;  // 256
    __shared__ float sty[128];
    __shared__ float red[256];
    if (t < 128) sty[t] = style[b * 128 + t] + 1.0f;
    __syncthreads();
    const int f = t & 127, half = t >> 7;
    const float* kp = kern + (size_t)rs * 16384 + f;
    float s = 0.0f;
    #pragma unroll 8
    for (int c = half * 64; c < half * 64 + 64; ++c) {
        float w = kp[(size_t)c * 128] * sty[c];
        s += w * w;
    }
    red[t] = s;
    __syncthreads();
    if (t < 128) partial[((size_t)b * 9 + rs) * 128 + t] = red[t] + red[t + 128];
}

// wt[b][rs][f][c] = bf16(kern[rs][c][f] * sty[c] * demod[f]), c-contig for LDS staging.
__global__ void prep_wt(const float* __restrict__ kern,
                        const float* __restrict__ style,
                        const float* __restrict__ partial,
                        unsigned short* __restrict__ wt) {
    const int rs = blockIdx.x, b = blockIdx.y;
    const int t  = threadIdx.x;  // 256
    __shared__ float sty[128], dm[128];
    __shared__ float ts[32][132];
    if (t < 128) {
        sty[t] = style[b * 128 + t] + 1.0f;
    } else {
        const int f = t - 128;
        float s = 0.0f;
        #pragma unroll
        for (int r = 0; r < 9; ++r) s += partial[((size_t)b * 9 + r) * 128 + f];
        dm[f] = rsqrtf(s + 1e-8f);
    }
    __syncthreads();
    const float* kp = kern + (size_t)rs * 16384;
    unsigned short* wp = wt + ((size_t)b * 9 + rs) * 16384;
    for (int c0 = 0; c0 < 128; c0 += 32) {
        {
            const int fi = (t & 31) * 4;
            const int ci = t >> 5;
            #pragma unroll
            for (int k = 0; k < 4; ++k) {
                const float4 v = *(const float4*)(kp + (size_t)(c0 + ci + 8 * k) * 128 + fi);
                ts[ci + 8 * k][fi + 0] = v.x;
                ts[ci + 8 * k][fi + 1] = v.y;
                ts[ci + 8 * k][fi + 2] = v.z;
                ts[ci + 8 * k][fi + 3] = v.w;
            }
        }
        __syncthreads();
        {
            const int cb = (t & 7) * 4;
            const int f2 = t >> 3;
            #pragma unroll
            for (int k = 0; k < 4; ++k) {
                const int f = f2 + 32 * k;
                ushort4 o;
                o.x = f2bf(ts[cb + 0][f] * sty[c0 + cb + 0] * dm[f]);
                o.y = f2bf(ts[cb + 1][f] * sty[c0 + cb + 1] * dm[f]);
                o.z = f2bf(ts[cb + 2][f] * sty[c0 + cb + 2] * dm[f]);
                o.w = f2bf(ts[cb + 3][f] * sty[c0 + cb + 3] * dm[f]);
                *(ushort4*)(wp + (size_t)f * 128 + c0 + cb) = o;
            }
        }
        __syncthreads();
    }
}

// ---------------- fused conv: x fp32 read once, cvt on the fly --------------
// Grid: 256 blocks = 8 b x 16 h-stripes x 2 F-halves (fh fastest => the fh-pair
// reading the same x rows runs concurrently -> L3 catches the second read).
// Block 512 thr (8 waves): wave wv = h-row (stripe*8+wv) x 128 w x 64 F.
// Per wave: mt=8 M-tiles, ft=4 F-tiles, acc 8x4x4 = 128 VGPR.
// Weights LDS-resident (pitch 132 el = 66 dw -> conflict-free ds_read_b128);
// single barrier after staging; A-frags straight from global (per (col,kc) the
// 4 quads cover exactly one 128B line of x).
__global__ __launch_bounds__(512, 2) void mdconv3(const float* __restrict__ x,
                                                  const unsigned short* __restrict__ wt,
                                                  float* __restrict__ out) {
    const int lin    = blockIdx.x;
    const int fh     = lin & 1;
    const int stripe = (lin >> 1) & 15;
    const int b      = lin >> 5;
    const int tid    = threadIdx.x;

    __shared__ unsigned short wtl[9 * 64 * 132];  // 152,064 B

    {   // stage wt[b][rs][fh*64+f][c] -> wtl[(rs*64+f)*132 + c]
        for (int idx = tid; idx < 576 * 16; idx += 512) {
            const int row = idx >> 4;
            const int c8  = idx & 15;
            const int rs  = row >> 6;
            const int f   = row & 63;
            *(ushort8*)(wtl + row * 132 + c8 * 8) =
                *(const ushort8*)(wt + (((size_t)b * 9 + rs) * 128 + fh * 64 + f) * 128 + c8 * 8);
        }
    }
    __syncthreads();  // the only barrier

    const int lane = tid & 63;
    const int wv   = tid >> 6;
    const int fl   = lane & 15;
    const int quad = lane >> 4;
    const int kq   = quad * 8;

    const int h = stripe * 8 + wv;   // this wave's output row

    f32x4 acc[8][4];
    #pragma unroll
    for (int mt = 0; mt < 8; ++mt)
        #pragma unroll
        for (int ft = 0; ft < 4; ++ft)
            acc[mt][ft] = (f32x4){0.f, 0.f, 0.f, 0.f};

    const float* xb = x + (size_t)b * (128 * 128 * 128);
    const unsigned short* wl = wtl + fl * 132 + kq;

    #pragma unroll
    for (int rs = 0; rs < 9; ++rs) {
        const int r = rs / 3, s = rs % 3;
        const int row = h + r - 1;
        if ((unsigned)row > 127u) continue;           // wave-uniform skip
        const float* xrow = xb + (size_t)row * (128 * 128);

        // per-mt lane base pointers (kq folded in; kc becomes an immediate)
        const float* bp[8];
        #pragma unroll
        for (int mt = 0; mt < 8; ++mt)
            bp[mt] = xrow + (size_t)(mt * 16 + fl + s - 1) * 128 + kq;

        #pragma unroll
        for (int kc = 0; kc < 4; ++kc) {
            short8 a[8];
            #pragma unroll
            for (int mt = 0; mt < 8; ++mt) {
                float4 v0 = {0.f, 0.f, 0.f, 0.f}, v1 = {0.f, 0.f, 0.f, 0.f};
                if ((mt == 0 && s == 0) || (mt == 7 && s == 2)) {  // folds at unroll
                    const int col = mt * 16 + fl + s - 1;
                    if ((unsigned)col < 128u) {
                        v0 = *(const float4*)(bp[mt] + kc * 32);
                        v1 = *(const float4*)(bp[mt] + kc * 32 + 4);
                    }
                } else {
                    v0 = *(const float4*)(bp[mt] + kc * 32);
                    v1 = *(const float4*)(bp[mt] + kc * 32 + 4);
                }
                short8 t;
                t[0] = (short)f2bf(v0.x); t[1] = (short)f2bf(v0.y);
                t[2] = (short)f2bf(v0.z); t[3] = (short)f2bf(v0.w);
                t[4] = (short)f2bf(v1.x); t[5] = (short)f2bf(v1.y);
                t[6] = (short)f2bf(v1.z); t[7] = (short)f2bf(v1.w);
                a[mt] = t;
            }
            short8 bf[4];
            #pragma unroll
            for (int ft = 0; ft < 4; ++ft)
                bf[ft] = *(const short8*)(wl + (size_t)rs * (64 * 132) + ft * 16 * 132 + kc * 32);
            #pragma unroll
            for (int mt = 0; mt < 8; ++mt)
                #pragma unroll
                for (int ft = 0; ft < 4; ++ft)
                    acc[mt][ft] =
                        __builtin_amdgcn_mfma_f32_16x16x32_bf16(a[mt], bf[ft], acc[mt][ft], 0, 0, 0);
        }
    }

    // D: col=lane&15 -> f within tile, row=quad*4+reg -> w within M-tile
    float* ob = out + ((size_t)(b * 128 + h) * 128) * 128;
    #pragma unroll
    for (int mt = 0; mt < 8; ++mt) {
        #pragma unroll
        for (int ft = 0; ft < 4; ++ft) {
            const int f = fh * 64 + ft * 16 + fl;
            #pragma unroll
            for (int reg = 0; reg < 4; ++reg) {
                const int w = mt * 16 + quad * 4 + reg;
                ob[(size_t)w * 128 + f] = acc[mt][ft][reg];
            }
        }
    }
}

extern "C" void kernel_launch(void* const* d_in, const int* in_sizes, int n_in,
                              void* d_out, int out_size, void* d_ws, size_t ws_size,
                              hipStream_t stream) {
    const float* x     = (const float*)d_in[0];
    const float* style = (const float*)d_in[1];
    const float* kern  = (const float*)d_in[2];
    float* out = (float*)d_out;

    const size_t WT_BYTES = (size_t)8 * 9 * 128 * 128 * 2;  // 2,359,296
    unsigned short* wt = (unsigned short*)d_ws;
    float* partial     = (float*)((char*)d_ws + WT_BYTES);

    prep_sumsq<<<dim3(9, 8), dim3(256), 0, stream>>>(kern, style, partial);
    prep_wt<<<dim3(9, 8), dim3(256), 0, stream>>>(kern, style, partial, wt);
    mdconv3<<<dim3(256), dim3(512), 0, stream>>>(x, wt, out);
}

// Round 6
// 221.889 us; speedup vs baseline: 1.3453x; 1.3453x over previous
//
#include <hip/hip_runtime.h>

typedef __attribute__((ext_vector_type(8))) short short8;
typedef __attribute__((ext_vector_type(8))) unsigned short ushort8;
typedef __attribute__((ext_vector_type(4))) float f32x4;

static __device__ __forceinline__ unsigned short f2bf(float f) {
    union { float f; unsigned int u; } a; a.f = f;
    unsigned int u = a.u;
    return (unsigned short)((u + 0x7fffu + ((u >> 16) & 1u)) >> 16);  // RNE
}
static __device__ __forceinline__ float bf2f(unsigned short h) {
    union { unsigned int u; float f; } a; a.u = ((unsigned int)h) << 16;
    return a.f;
}

// ---------------- x -> padded bf16 NHWC [8][130][130][128] ----------------
// Zero border => main loop has NO bounds checks. (R3-proven kernel, unchanged.)
#define PPLANE 2163200  // 130*130*128
__global__ void cvt_x(const float* __restrict__ x, unsigned short* __restrict__ xbf) {
    const int id = blockIdx.x * 256 + threadIdx.x;  // one ushort8 chunk
    if (id >= 8 * 130 * 130 * 16) return;
    const int cg = id & 15;
    const int p  = id >> 4;
    const int wp = p % 130;
    const int q  = p / 130;
    const int hp = q % 130;
    const int b  = q / 130;
    ushort8 v = {0, 0, 0, 0, 0, 0, 0, 0};
    if (hp >= 1 && hp <= 128 && wp >= 1 && wp <= 128) {
        const float4* src = (const float4*)(x + (((size_t)b * 128 + (hp - 1)) * 128 + (wp - 1)) * 128 + cg * 8);
        float4 f0 = src[0];
        float4 f1 = src[1];
        v[0] = f2bf(f0.x); v[1] = f2bf(f0.y); v[2] = f2bf(f0.z); v[3] = f2bf(f0.w);
        v[4] = f2bf(f1.x); v[5] = f2bf(f1.y); v[6] = f2bf(f1.z); v[7] = f2bf(f1.w);
    }
    *(ushort8*)(xbf + (size_t)p * 128 + cg * 8) = v;
}

// ---------------- fused conv: in-block weight prep + MFMA main loop ---------
// Grid 256 = 8 b x 16 h-stripes x 2 F-halves. Block 512 thr (8 waves).
// Prologue (per block, ~2 us): compute this block's 64-F modulated+demodulated
// bf16 weight slice DIRECTLY into LDS from kern+style (kern 2.36 MB, L2-hot).
// No global wt buffer, no prep dispatches -> minimal state surface + no gaps.
// Main loop: mdconv3's PROVEN structure (simple unrolled loads, one barrier
// chain, compiler scheduling): wave = 1 h-row x 128 w x 64 F, mt=8, ft=4.
__global__ __launch_bounds__(512, 2) void mdconv_f(const unsigned short* __restrict__ xbf,
                                                   const float* __restrict__ kern,
                                                   const float* __restrict__ style,
                                                   float* __restrict__ out) {
    const int lin    = blockIdx.x;
    const int fh     = lin & 1;
    const int stripe = (lin >> 1) & 15;
    const int b      = lin >> 5;
    const int tid    = threadIdx.x;

    __shared__ unsigned short wtl[9 * 64 * 132];  // 152,064 B (pitch 132)
    __shared__ float sty[128];
    __shared__ float dmred[8][72];
    __shared__ float dm[64];

    if (tid < 128) sty[tid] = style[b * 128 + tid] + 1.0f;
    __syncthreads();

    {   // phase A: modulate -> bf16 into wtl (pre-demod), accumulate sumsq per f
        const int f  = tid & 63;        // f within this fh-half
        const int cg = tid >> 6;        // c-group: c = cg*16 .. +16
        const float* kp = kern + fh * 64 + f;   // kern[rs][c][fglob], f-contig last
        float sq = 0.0f;
        #pragma unroll
        for (int rs = 0; rs < 9; ++rs) {
            #pragma unroll
            for (int half = 0; half < 2; ++half) {
                ushort8 buf;
                #pragma unroll
                for (int i = 0; i < 8; ++i) {
                    const int c = cg * 16 + half * 8 + i;
                    const float w = kp[(size_t)(rs * 128 + c) * 128] * sty[c];
                    sq += w * w;
                    buf[i] = f2bf(w);
                }
                *(ushort8*)(wtl + (rs * 64 + f) * 132 + cg * 16 + half * 8) = buf;
            }
        }
        dmred[cg][f] = sq;
    }
    __syncthreads();
    if (tid < 64) {
        float s = 0.0f;
        #pragma unroll
        for (int j = 0; j < 8; ++j) s += dmred[j][tid];
        dm[tid] = rsqrtf(s + 1e-8f);
    }
    __syncthreads();
    {   // phase B: scale wtl rows by dm[f]
        for (int idx = tid; idx < 576 * 16; idx += 512) {
            const int row = idx >> 4;
            const int c8  = idx & 15;
            const float d = dm[row & 63];
            ushort8 v = *(const ushort8*)(wtl + row * 132 + c8 * 8);
            #pragma unroll
            for (int i = 0; i < 8; ++i) v[i] = f2bf(bf2f(v[i]) * d);
            *(ushort8*)(wtl + row * 132 + c8 * 8) = v;
        }
    }
    __syncthreads();

    // ---------------- main loop (mdconv3-proven structure) ----------------
    const int lane = tid & 63;
    const int wv   = tid >> 6;
    const int fl   = lane & 15;
    const int quad = lane >> 4;
    const int kq   = quad * 8;

    const int h = stripe * 8 + wv;  // output row

    f32x4 acc[8][4];
    #pragma unroll
    for (int mt = 0; mt < 8; ++mt)
        #pragma unroll
        for (int ft = 0; ft < 4; ++ft)
            acc[mt][ft] = (f32x4){0.f, 0.f, 0.f, 0.f};

    const unsigned short* xb = xbf + (size_t)b * PPLANE;
    const unsigned short* wl = wtl + fl * 132 + kq;

    #pragma unroll
    for (int rs = 0; rs < 9; ++rs) {
        const int r = rs / 3, s = rs % 3;
        // padded coords: hp = h + r, wp = mt*16 + fl + s  (borders are zeros)
        const unsigned short* arow = xb + ((size_t)(h + r) * 130 + fl + s) * 128 + kq;
        const unsigned short* brow = wl + rs * 8448;  // 8448 = 64*132
        #pragma unroll
        for (int kc = 0; kc < 4; ++kc) {
            short8 a[8];
            #pragma unroll
            for (int mt = 0; mt < 8; ++mt)
                a[mt] = *(const short8*)(arow + mt * 2048 + kc * 32);   // 2048 = 16*128
            short8 bf[4];
            #pragma unroll
            for (int ft = 0; ft < 4; ++ft)
                bf[ft] = *(const short8*)(brow + ft * 2112 + kc * 32);  // 2112 = 16*132
            #pragma unroll
            for (int mt = 0; mt < 8; ++mt)
                #pragma unroll
                for (int ft = 0; ft < 4; ++ft)
                    acc[mt][ft] =
                        __builtin_amdgcn_mfma_f32_16x16x32_bf16(a[mt], bf[ft], acc[mt][ft], 0, 0, 0);
        }
    }

    // D: col=lane&15 -> f within tile, row=quad*4+reg -> w within M-tile
    float* ob = out + ((size_t)(b * 128 + h) * 128) * 128;
    #pragma unroll
    for (int mt = 0; mt < 8; ++mt) {
        #pragma unroll
        for (int ft = 0; ft < 4; ++ft) {
            const int f = fh * 64 + ft * 16 + fl;
            #pragma unroll
            for (int reg = 0; reg < 4; ++reg) {
                const int w = mt * 16 + quad * 4 + reg;
                ob[(size_t)w * 128 + f] = acc[mt][ft][reg];
            }
        }
    }
}

extern "C" void kernel_launch(void* const* d_in, const int* in_sizes, int n_in,
                              void* d_out, int out_size, void* d_ws, size_t ws_size,
                              hipStream_t stream) {
    const float* x     = (const float*)d_in[0];
    const float* style = (const float*)d_in[1];
    const float* kern  = (const float*)d_in[2];
    float* out = (float*)d_out;

    unsigned short* xbf = (unsigned short*)d_ws;  // 34,611,200 B (ws proven >= 37 MB in R3)

    cvt_x<<<dim3((8 * 130 * 130 * 16 + 255) / 256), dim3(256), 0, stream>>>(x, xbf);
    mdconv_f<<<dim3(256), dim3(512), 0, stream>>>(xbf, kern, style, out);
}